// Round 5
// baseline (142481.653 us; speedup 1.0000x reference)
//
#include <hip/hip_runtime.h>
#include <cmath>

#define BATCH 128
#define TLEN  256
#define HDIM  1024
#define CDIM  10
#define NT    1024
#define NWG   256

typedef unsigned long long u64;
typedef unsigned int u32;

// h state, TRIPLE buffered (R14 protocol), k-major, u64 = 2 packed floats:
// g_hx[buf][j][b/2]. Production p lives in buf p%3. WAR proof: a block writes
// production t+1 only after its chunk gates (or fast probe) saw ALL 128 group
// flags >= t+1, i.e. every block finished step t-1 and a fortiori its reads of
// production t-2 -- which shares the buffer slot ((t+1)%3 == (t-2)%3). QED.
__device__ u64 g_hx[3][HDIM][BATCH / 2];

// R15: repacked weights [jp][k][8] = (j0:g,i,f,o, j1:g,i,f,o), jp = j/2.
// Wave-uniform address -> scalar/broadcast path; W never touches LDS.
__device__ float g_Wp[(HDIM / 2) * HDIM * 8];   // 16 MB

__device__ __forceinline__ float4 ld4(const float* p) { return *(const float4*)p; }

__device__ __forceinline__ u64 aload(const u64* p) {
    return __hip_atomic_load(p, __ATOMIC_RELAXED, __HIP_MEMORY_SCOPE_AGENT);
}
__device__ __forceinline__ void astore(u64* p, u64 v) {
    __hip_atomic_store(p, v, __ATOMIC_RELAXED, __HIP_MEMORY_SCOPE_AGENT);
}
__device__ __forceinline__ void astore32(u32* p, u32 v) {
    __hip_atomic_store(p, v, __ATOMIC_RELAXED, __HIP_MEMORY_SCOPE_AGENT);
}

// LDS-only barrier (R13): intra-block barriers only protect LDS handoffs.
__device__ __forceinline__ void barrier_lds() {
    asm volatile("s_waitcnt lgkmcnt(0)\n\ts_barrier" ::: "memory");
}

// R14 dataflow sync. flags[grp*128 + z] = productions completed by block z of
// group grp (monotonic, memset 0 per launch, init production = 1).
// Chunk c (64 k-rows) producers are blocks 8c..8c+7 (8 j-rows per block).

__device__ __forceinline__ void gate16(const u32* flags, int grp, u32 target) {
    const u64* base = (const u64*)(flags + grp * 128);
    const int sl = threadIdx.x & 7;
    int guard = 0;
    for (;;) {
        const u64 v = aload(base + sl);
        const bool ok = ((u32)v >= target) && ((u32)(v >> 32) >= target);
        if (__all(ok) || ++guard > (1 << 20)) break;
        __builtin_amdgcn_s_sleep(1);
    }
    asm volatile("" ::: "memory");
}

__device__ __forceinline__ bool probe128(const u32* flags, int grp, u32 target) {
    const u64 v = aload((const u64*)(flags + grp * 128) + (threadIdx.x & 63));
    return __all(((u32)v >= target) && ((u32)(v >> 32) >= target));
}

__device__ __forceinline__ void wait_chunk8(const u32* flags, int grp, int c, u32 target) {
    const u64* p = (const u64*)(flags + grp * 128) + 4 * c;
    int guard = 0;
    for (;;) {
        const u64 a = aload(p);
        const u64 b = aload(p + 1);
        const u64 d = aload(p + 2);
        const u64 e = aload(p + 3);
        const bool ok = ((u32)a >= target) && ((u32)(a >> 32) >= target) &&
                        ((u32)b >= target) && ((u32)(b >> 32) >= target) &&
                        ((u32)d >= target) && ((u32)(d >> 32) >= target) &&
                        ((u32)e >= target) && ((u32)(e >> 32) >= target);
        if (ok || ++guard > (1 << 20)) break;
        __builtin_amdgcn_s_sleep(1);
    }
    asm volatile("" ::: "memory");
}

__device__ __forceinline__ void wait_all(const u32* flags, int grp, u32 target) {
    const u64* base = (const u64*)(flags + grp * 128) + (threadIdx.x & 63);
    int guard = 0;
    for (;;) {
        const u64 v = aload(base);
        const bool ok = ((u32)v >= target) && ((u32)(v >> 32) >= target);
        if (__all(ok) || ++guard > (1 << 20)) break;
        __builtin_amdgcn_s_sleep(1);
    }
    asm volatile("" ::: "memory");
}

#define FMA4(d, s, v) do { (d).x = fmaf((s), (v).x, (d).x); (d).y = fmaf((s), (v).y, (d).y); \
                           (d).z = fmaf((s), (v).z, (d).z); (d).w = fmaf((s), (v).w, (d).w); } while (0)
#define ADD4(d, s)     do { (d).x += (s).x; (d).y += (s).y; (d).z += (s).z; (d).w += (s).w; } while (0)

// One-time weight repack: g_Wp[jp][k][8] = {Wgh,Wih,Wfh,Woh}[2jp][k], then [2jp+1][k].
__global__ void repack_w(const float* __restrict__ Wgh, const float* __restrict__ Wih,
                         const float* __restrict__ Wfh, const float* __restrict__ Woh) {
    const int jp = blockIdx.x;                 // 0..511
    const size_t j0 = (size_t)jp * 2, j1 = j0 + 1;
    float* dst = g_Wp + (size_t)jp * HDIM * 8;
    for (int k = threadIdx.x; k < HDIM; k += blockDim.x) {
        const float4 a = make_float4(Wgh[j0 * HDIM + k], Wih[j0 * HDIM + k],
                                     Wfh[j0 * HDIM + k], Woh[j0 * HDIM + k]);
        const float4 b = make_float4(Wgh[j1 * HDIM + k], Wih[j1 * HDIM + k],
                                     Wfh[j1 * HDIM + k], Woh[j1 * HDIM + k]);
        *(float4*)(dst + (size_t)k * 8)     = a;
        *(float4*)(dst + (size_t)k * 8 + 4) = b;
    }
}

// R15 compute core: lanes = b. Wave w: jq = w>>2 (j-pair), kq = w&3 (k-quarter,
// 256 k). Per chunk (64 k) the wave consumes its 16-k slice from a TRANSPOSED
// LDS tile sT[b][k] (column-XOR swizzled; write & read use the same involution).
// Weights arrive wave-uniform from g_Wp (scalar/broadcast pipe, zero LDS).
// k is lane-local -> NO shuffle butterfly; one LDS exchange over kq per step.
// Epilogue on kq==0 waves: 2 cells (j0,j1) per lane, coalesced h-writes.
__global__ void __launch_bounds__(NT, 1)
lstm_fused(const float* __restrict__ x,
           const float* __restrict__ Wgx, const float* __restrict__ Wgh, const float* __restrict__ bg,
           const float* __restrict__ Wix, const float* __restrict__ Wih, const float* __restrict__ bi,
           const float* __restrict__ Wfx, const float* __restrict__ Wfh, const float* __restrict__ bf,
           const float* __restrict__ Wox, const float* __restrict__ Woh, const float* __restrict__ bo,
           const float* __restrict__ Wph, const float* __restrict__ bp,
           u32* __restrict__ flags, float* __restrict__ out)
{
    __shared__ __align__(16) float sT[2][64][68];      // h chunk dbuf, 34.8 KB
    __shared__ __align__(16) float sX[TLEN][64];       // x transposed, 64 KB (reused by projection)
    __shared__ __align__(16) float sR[4][3][64][8];    // kq exchange, 24.5 KB

    const int tid  = threadIdx.x;
    const int wave = tid >> 6;
    const int lane = tid & 63;                          // = local b
    const int jq   = __builtin_amdgcn_readfirstlane(wave >> 2);
    const int kq   = __builtin_amdgcn_readfirstlane(wave & 3);
    const int rgB  = blockIdx.x >> 1;   // j in [8*rgB, 8*rgB+8); group index
    const int bgB  = blockIdx.x & 1;    // b-half group id

    const int kp  = tid >> 5;           // staging: k-pair in chunk (0..31)
    const int bpr = tid & 31;           // staging: b-pair (0..31)  [renamed: 'bp' is a param]
    const int xr  = 4 * ((lane >> 1) & 7);    // read-side column XOR (dwords)
    const int ss  = (lane >> 2) & 1;          // sR slot swap (write/read symmetric)

    const float* wbase = g_Wp + (size_t)(rgB * 4 + jq) * (HDIM * 8);

    // epilogue constants (wave-uniform): j0 = rgB*8+jq*2, j1 = j0+1
    const int j0 = rgB * 8 + jq * 2, j1 = j0 + 1;
    const float4 wx0 = make_float4(Wgx[j0], Wix[j0], Wfx[j0], Wox[j0]);
    const float4 bb0 = make_float4(bg[j0], bi[j0], bf[j0], bo[j0]);
    const float4 wx1 = make_float4(Wgx[j1], Wix[j1], Wfx[j1], Wox[j1]);
    const float4 bb1 = make_float4(bg[j1], bi[j1], bf[j1], bo[j1]);
    float cst0 = 0.f, cst1 = 0.f;

    // ---- stage x transposed into sX[t][b] (once) ----
    for (int i = tid; i < TLEN * 64 / 4; i += NT) {
        const int bl = i >> 6;                 // local b (0..63)
        const int tq = i & 63;                 // float4 index within the T row
        const float4 v = ld4(x + (size_t)(bgB * 64 + bl) * TLEN + tq * 4);
        sX[tq * 4 + 0][bl] = v.x; sX[tq * 4 + 1][bl] = v.y;
        sX[tq * 4 + 2][bl] = v.z; sX[tq * 4 + 3][bl] = v.w;
    }

    // zero h0 (production 0, buf 0) -- OWN b-half: 8 j-rows x 32 u64
    if (tid < 256)
        astore(&g_hx[0][rgB * 8 + (tid >> 5)][bgB * 32 + (tid & 31)], 0ull);

    // publish production 0 (drain h writes, order sX, bump flag)
    asm volatile("s_waitcnt vmcnt(0)" ::: "memory");
    __syncthreads();
    if (tid == 0) astore32(flags + bgB * 128 + rgB, 1u);

    const int hcol = bgB * 32 + bpr;           // u64 col in g_hx row
    const int cwu  = kp ^ (2 * (bpr & 7));     // swizzled u64 col in sT row

#define SLOAD(CC) do { \
        const u64* hr_ = hc + ((size_t)((CC) * 64 + 2 * kp)) * 64 + hcol; \
        A0 = aload(hr_); A1 = aload(hr_ + 64); } while (0)

    // transpose 2x2: rows 2bpr/2bpr+1 get (k0,k1) pairs; both rows share cwu.
#define SWRITE(TB) do { \
        u64* tp_ = (u64*)&(TB)[0][0]; \
        const u64 r0_ = ((u64)(u32)A0) | (((u64)(u32)A1) << 32); \
        const u64 r1_ = (A0 >> 32) | (A1 & 0xffffffff00000000ull); \
        tp_[(2 * bpr) * 34 + cwu]     = r0_; \
        tp_[(2 * bpr + 1) * 34 + cwu] = r1_; } while (0)

#define COMPUTE(CC, TB) do { \
        const float* tb_ = &(TB)[0][0] + lane * 68; \
        const float* wp_ = wbase + (size_t)((CC) * 64 + kq * 16) * 8; \
        _Pragma("unroll") \
        for (int k4 = 0; k4 < 4; ++k4) { \
            const float4 h4 = ld4(tb_ + ((kq * 16 + k4 * 4) ^ xr)); \
            const float4 wa0 = ld4(wp_ + k4 * 32 +  0), wb0 = ld4(wp_ + k4 * 32 +  4); \
            const float4 wa1 = ld4(wp_ + k4 * 32 +  8), wb1 = ld4(wp_ + k4 * 32 + 12); \
            const float4 wa2 = ld4(wp_ + k4 * 32 + 16), wb2 = ld4(wp_ + k4 * 32 + 20); \
            const float4 wa3 = ld4(wp_ + k4 * 32 + 24), wb3 = ld4(wp_ + k4 * 32 + 28); \
            FMA4(acc0, h4.x, wa0); FMA4(acc1, h4.x, wb0); \
            FMA4(acc0, h4.y, wa1); FMA4(acc1, h4.y, wb1); \
            FMA4(acc0, h4.z, wa2); FMA4(acc1, h4.z, wb2); \
            FMA4(acc0, h4.w, wa3); FMA4(acc1, h4.w, wb3); \
        } } while (0)

    int cb_ = 0;                               // t % 3 (consume buffer)
    for (int t = 0; t < TLEN; ++t) {
        const int nb_ = (cb_ == 2) ? 0 : cb_ + 1;
        const u32 tgt = (u32)(t + 1);
        const u64* hc = &g_hx[cb_][0][0];
        u32*       hn32 = (u32*)&g_hx[nb_][0][0];
        u64 A0, A1;

        gate16(flags, bgB, tgt);               // producers of chunks 0,1 ready
        SLOAD(0);
        const bool fast = probe128(flags, bgB, tgt);   // overlaps chunk-0 latency
        SWRITE(sT[0]);
        barrier_lds();

        float4 acc0 = make_float4(0.f, 0.f, 0.f, 0.f);
        float4 acc1 = make_float4(0.f, 0.f, 0.f, 0.f);

        #pragma unroll 1
        for (int c2 = 0; c2 < 8; ++c2) {
            const int e0 = c2 * 2;
            // even chunk: compute buf0, stage e0+1 -> buf1
            if (!fast) wait_chunk8(flags, bgB, e0 + 1, tgt);
            SLOAD(e0 + 1);                     // issue early, hide under FMAs
            COMPUTE(e0, sT[0]);
            SWRITE(sT[1]);
            barrier_lds();
            // odd chunk: compute buf1, stage e0+2 -> buf0
            if (e0 + 2 < 16) {
                if (!fast) wait_chunk8(flags, bgB, e0 + 2, tgt);
                SLOAD(e0 + 2);
            }
            COMPUTE(e0 + 1, sT[1]);
            if (e0 + 2 < 16) SWRITE(sT[0]);
            barrier_lds();
        }

        // ---- cross-kq exchange (single stage; k lane-local -> no shuffles) ----
        if (kq != 0) {
            float* dst = &sR[jq][kq - 1][lane][0];
            *(float4*)(dst + 4 * ss)       = acc0;   // slot swap halves write conflicts
            *(float4*)(dst + 4 * (1 - ss)) = acc1;
        }
        barrier_lds();

        if (kq == 0) {
            #pragma unroll
            for (int r = 0; r < 3; ++r) {
                const float* s = &sR[jq][r][lane][0];
                const float4 p0 = ld4(s + 4 * ss), p1 = ld4(s + 4 * (1 - ss));
                ADD4(acc0, p0); ADD4(acc1, p1);
            }
            const float xv = sX[t][lane];
            FMA4(acc0, xv, wx0);
            acc0.x += bb0.x; acc0.y += bb0.y; acc0.z += bb0.z; acc0.w += bb0.w;
            FMA4(acc1, xv, wx1);
            acc1.x += bb1.x; acc1.y += bb1.y; acc1.z += bb1.z; acc1.w += bb1.w;

            const float g0 = tanhf(acc0.x);
            const float i0 = 1.f / (1.f + expf(-acc0.y));
            const float f0 = 1.f / (1.f + expf(-acc0.z));
            const float o0 = 1.f / (1.f + expf(-acc0.w));
            cst0 = g0 * i0 + cst0 * f0;
            const float h0v = tanhf(cst0) * o0;

            const float g1 = tanhf(acc1.x);
            const float i1 = 1.f / (1.f + expf(-acc1.y));
            const float f1 = 1.f / (1.f + expf(-acc1.z));
            const float o1 = 1.f / (1.f + expf(-acc1.w));
            cst1 = g1 * i1 + cst1 * f1;
            const float h1v = tanhf(cst1) * o1;

            u32 bits0, bits1;
            __builtin_memcpy(&bits0, &h0v, 4);
            __builtin_memcpy(&bits1, &h1v, 4);
            astore32(hn32 + (size_t)j0 * BATCH + bgB * 64 + lane, bits0);
            astore32(hn32 + (size_t)j1 * BATCH + bgB * 64 + lane, bits1);
        }

        // ---- publish production t+1 ----
        asm volatile("s_waitcnt vmcnt(0)" ::: "memory");
        __syncthreads();
        if (tid == 0) astore32(flags + bgB * 128 + rgB, (u32)(t + 2));
        cb_ = nb_;
    } // t
#undef COMPUTE
#undef SWRITE
#undef SLOAD

    // ---- final projection: out = h_final @ W_ph + bias_p (h in buf TLEN%3 == 1) ----
    wait_all(flags, bgB, (u32)(TLEN + 1));
    if (rgB < 64) {
        const int b = bgB * 64 + rgB;
        float part[CDIM];
        #pragma unroll
        for (int c2 = 0; c2 < CDIM; ++c2) part[c2] = 0.f;
        for (int k = tid; k < HDIM; k += NT) {
            const u64 hvu = aload(&g_hx[TLEN % 3][k][b >> 1]);
            float2 hv2; __builtin_memcpy(&hv2, &hvu, 8);
            const float hvv = (b & 1) ? hv2.y : hv2.x;
            #pragma unroll
            for (int c2 = 0; c2 < CDIM; ++c2)
                part[c2] = fmaf(hvv, Wph[(size_t)k * CDIM + c2], part[c2]);
        }
        float* red = &sX[0][0];                // 49 KB needed <= 64 KB
        #pragma unroll
        for (int c2 = 0; c2 < CDIM; ++c2) red[tid * 12 + c2] = part[c2];
        __syncthreads();
        for (int s = NT / 2; s > 0; s >>= 1) {
            if (tid < s) {
                #pragma unroll
                for (int c2 = 0; c2 < CDIM; ++c2)
                    red[tid * 12 + c2] += red[(tid + s) * 12 + c2];
            }
            __syncthreads();
        }
        if (tid < CDIM) out[(size_t)b * CDIM + tid] = red[tid] + bp[tid];
    }
}

extern "C" void kernel_launch(void* const* d_in, const int* in_sizes, int n_in,
                              void* d_out, int out_size, void* d_ws, size_t ws_size,
                              hipStream_t stream) {
    const float* x   = (const float*)d_in[0];
    const float* Wgx = (const float*)d_in[1];
    const float* Wgh = (const float*)d_in[2];
    const float* bg  = (const float*)d_in[3];
    const float* Wix = (const float*)d_in[4];
    const float* Wih = (const float*)d_in[5];
    const float* bi  = (const float*)d_in[6];
    const float* Wfx = (const float*)d_in[7];
    const float* Wfh = (const float*)d_in[8];
    const float* bf  = (const float*)d_in[9];
    const float* Wox = (const float*)d_in[10];
    const float* Woh = (const float*)d_in[11];
    const float* bo  = (const float*)d_in[12];
    const float* Wph = (const float*)d_in[13];
    const float* bp  = (const float*)d_in[14];
    u32* flags = (u32*)d_ws;               // u32[2][128] monotonic production counters
    float* out = (float*)d_out;

    (void)hipMemsetAsync(d_ws, 0, 2 * 128 * sizeof(u32), stream);   // capturable node

    // one-time (per launch) weight repack into g_Wp
    repack_w<<<dim3(HDIM / 2), dim3(256), 0, stream>>>(Wgh, Wih, Wfh, Woh);

    void* args[] = {&x, &Wgx, &Wgh, &bg, &Wix, &Wih, &bi, &Wfx, &Wfh, &bf,
                    &Wox, &Woh, &bo, &Wph, &bp, &flags, &out};
    hipError_t rc = hipLaunchCooperativeKernel((void*)lstm_fused, dim3(NWG), dim3(NT),
                                               args, 0, stream);
    if (rc != hipSuccess) {
        // Dataflow sync needs no cooperative-runtime support; 256 blocks at
        // 1 block/CU are fully co-resident under a regular launch too.
        lstm_fused<<<dim3(NWG), dim3(NT), 0, stream>>>(
            x, Wgx, Wgh, bg, Wix, Wih, bi, Wfx, Wfh, bf,
            Wox, Woh, bo, Wph, bp, flags, out);
    }
}

// Round 6
// 13898.322 us; speedup vs baseline: 10.2517x; 10.2517x over previous
//
#include <hip/hip_runtime.h>
#include <cmath>

#define BATCH 128
#define TLEN  256
#define HDIM  1024
#define CDIM  10
#define NT    1024
#define NWG   256

typedef unsigned long long u64;
typedef unsigned int u32;

// h state, double buffered, k-major, u64 = 2 packed floats: g_hx[buf][j][b/2].
// ALL h accesses are relaxed agent-scope atomics (sc1) -> no cache fences;
// x/W/bias stay warm in L1/L2 across all 256 steps.
__device__ u64 g_hx[2][HDIM][BATCH / 2];

__device__ __forceinline__ float4 ld4(const float* p) { return *(const float4*)p; }

__device__ __forceinline__ u64 aload(const u64* p) {
    return __hip_atomic_load(p, __ATOMIC_RELAXED, __HIP_MEMORY_SCOPE_AGENT);
}
__device__ __forceinline__ void astore(u64* p, u64 v) {
    __hip_atomic_store(p, v, __ATOMIC_RELAXED, __HIP_MEMORY_SCOPE_AGENT);
}
__device__ __forceinline__ void astore32(u32* p, u32 v) {
    __hip_atomic_store(p, v, __ATOMIC_RELAXED, __HIP_MEMORY_SCOPE_AGENT);
}

// R13: LDS-only barrier (intra-block barriers only protect LDS handoffs).
__device__ __forceinline__ void barrier_lds() {
    asm volatile("s_waitcnt lgkmcnt(0)\n\ts_barrier" ::: "memory");
}

// Group barrier (R11/R12-proven): parallel arrivals on 128 distinct flags,
// per-wave self-release poll, monotonic targets, bounded spin.
// Keeps its explicit vmcnt(0): it is the h-publish release fence.
__device__ __forceinline__ void gbar2(u32* flags, int grp, int idx, u32 target) {
    asm volatile("s_waitcnt vmcnt(0)" ::: "memory");
    __syncthreads();
    if (threadIdx.x == 0)
        astore32(flags + grp * 128 + idx, target);
    const u64* base = (const u64*)(flags + grp * 128) + (threadIdx.x & 63);
    int guard = 0;
    for (;;) {
        const u64 v = aload(base);
        const bool ok = ((u32)v >= target) && ((u32)(v >> 32) >= target);
        if (__all(ok) || ++guard > (1 << 20)) break;
        __builtin_amdgcn_s_sleep(1);
    }
}

#define FMA4(d, s, v) do { (d).x = fmaf((s), (v).x, (d).x); (d).y = fmaf((s), (v).y, (d).y); \
                           (d).z = fmaf((s), (v).z, (d).z); (d).w = fmaf((s), (v).w, (d).w); } while (0)
#define ADD4(d, s)     do { (d).x += (s).x; (d).y += (s).y; (d).z += (s).z; (d).w += (s).w; } while (0)

// R16: software-pipelined phases. h staging TRIPLE-buffered in LDS (chunk c in
// buf c%3); phase p prefetches chunk p+1's h-operands into registers while the
// FMAs of chunk p run on registers prefetched in phase p-1 -> the conflicted
// h ds_read latency is hidden under the FMA burst instead of serializing it.
// Hazards: write chunk p+2 (buf (p+2)%3) in phase p; that buf's last readers
// were phase p-2's prefetch of chunk p-1 -- two barriers intervene. QED.
// Global prefetch: 4 regs A..D, issue chunk p+6 in phase p, consume (ds_write)
// in phase p+4 -> ~4-phase MALL latency window.
__global__ void __launch_bounds__(NT, 1)
lstm_fused(const float* __restrict__ x,
           const float* __restrict__ Wgx, const float* __restrict__ Wgh, const float* __restrict__ bg,
           const float* __restrict__ Wix, const float* __restrict__ Wih, const float* __restrict__ bi,
           const float* __restrict__ Wfx, const float* __restrict__ Wfh, const float* __restrict__ bf,
           const float* __restrict__ Wox, const float* __restrict__ Woh, const float* __restrict__ bo,
           const float* __restrict__ Wph, const float* __restrict__ bp,
           u32* __restrict__ flags, float* __restrict__ out)
{
    __shared__ float sW[8][HDIM][4];            // [j_local][k][gate], 128 KB
    __shared__ __align__(16) float sHraw[3 * 32 * 68];   // h TRIPLE buf, 26.1 KB; sS aliases after last phase

    const int tid  = threadIdx.x;
    const int wave = tid >> 6;          // 0..15
    const int jq   = wave >> 2;         // j-pair index (0..3)
    const int kh   = wave & 3;          // k-quarter within chunk
    const int lane = tid & 63;
    const int ks   = lane & 7;
    const int bo8  = lane >> 3;
    const int rgB  = blockIdx.x >> 1;   // j in [8*rgB, 8*rgB+8)  == index in group
    const int bgB  = blockIdx.x & 1;    // b in [64*bgB, 64*bgB+64) == group id

    // ---- stage W once, gate-interleaved (1024 threads: 4 rows per pass) ----
    {
        auto stageW = [&](const float* Wsrc, int g) {
            #pragma unroll
            for (int it = 0; it < 2; ++it) {
                const int row = it * 4 + (tid >> 8);     // 0..7
                const int c4  = tid & 255;               // float4 column
                const float4 v = ld4(Wsrc + (size_t)(rgB * 8 + row) * HDIM + c4 * 4);
                sW[row][c4 * 4 + 0][g] = v.x;
                sW[row][c4 * 4 + 1][g] = v.y;
                sW[row][c4 * 4 + 2][g] = v.z;
                sW[row][c4 * 4 + 3][g] = v.w;
            }
        };
        stageW(Wgh, 0); stageW(Wih, 1); stageW(Wfh, 2); stageW(Woh, 3);
    }

    // epilogue cells: j = rgB*8 + jq*2 + (ks>>2); b = bgB*64 + bo8*8 + (ks&3)*2 + cell.
    const int jc = rgB * 8 + jq * 2 + (ks >> 2);
    const float4 wx4 = make_float4(Wgx[jc], Wix[jc], Wfx[jc], Wox[jc]);
    const float4 b4  = make_float4(bg[jc], bi[jc], bf[jc], bo[jc]);
    const int bloc = bgB * 64 + bo8 * 8 + (ks & 3) * 2;   // cell-0 batch index
    float cst = 0.f;                                       // my cell's c-state

    // zero h0 -- OWN b-half only: 8 j-rows x 32 u64
    if (tid < 256)
        astore(&g_hx[0][rgB * 8 + (tid >> 5)][bgB * 32 + (tid & 31)], 0ull);

    gbar2(flags, bgB, rgB, 1u);

    const int skc = tid >> 5;                   // staging: k within chunk (0..31)
    const int sbu = tid & 31;                   // staging: u64 col within 32
    const int hb0 = bgB * 32 + sbu;             // staging: u64 offset in g_hx row
    const int swoff = skc * 34 + sbu;           // u64 slot inside a buffer
    const int kc_ = kh * 8 + ks;                // this lane's k within any chunk

    // PHASE(P, G): prefetch chunk P+1 -> (hAn,hBn); ds_write chunk P+2 from G;
    // reissue G = chunk P+6; FMA chunk P from (hAc,hBc); barrier; swap regs.
    // FMA sequence identical to the proven COMP macro -> bitwise-identical acc.
#define PHASE(P, G)                                                             \
    {                                                                           \
        if ((P) + 1 < 32) {                                                     \
            const float* pp_ = &sHraw[bnF + kc_ * 68 + bo8 * 8];                \
            hAn = ld4(pp_); hBn = ld4(pp_ + 4);                                 \
            bnF += 2176; if (bnF > 4352) bnF = 0;                               \
        }                                                                       \
        if ((P) + 2 < 32) {                                                     \
            ((u64*)sHraw)[bwU + swoff] = G;                                     \
            bwU += 1088; if (bwU > 2176) bwU = 0;                               \
        }                                                                       \
        if ((P) + 6 < 32) G = aload(hrow + (size_t)((P) + 6) * 2048);           \
        {                                                                       \
            const float4 w0 = ld4(&sW[jq * 2 + 0][(P) * 32 + kc_][0]);          \
            const float4 w1 = ld4(&sW[jq * 2 + 1][(P) * 32 + kc_][0]);          \
            FMA4(acc[0][0], hAc.x, w0); FMA4(acc[0][1], hAc.y, w0);             \
            FMA4(acc[0][2], hAc.z, w0); FMA4(acc[0][3], hAc.w, w0);             \
            FMA4(acc[0][4], hBc.x, w0); FMA4(acc[0][5], hBc.y, w0);             \
            FMA4(acc[0][6], hBc.z, w0); FMA4(acc[0][7], hBc.w, w0);             \
            FMA4(acc[1][0], hAc.x, w1); FMA4(acc[1][1], hAc.y, w1);             \
            FMA4(acc[1][2], hAc.z, w1); FMA4(acc[1][3], hAc.w, w1);             \
            FMA4(acc[1][4], hBc.x, w1); FMA4(acc[1][5], hBc.y, w1);             \
            FMA4(acc[1][6], hBc.z, w1); FMA4(acc[1][7], hBc.w, w1);             \
        }                                                                       \
        barrier_lds();                                                          \
        hAc = hAn; hBc = hBn;                                                   \
    }

    for (int t = 0; t < TLEN; ++t) {
        const u64* hc = &g_hx[t & 1][0][0];
        u32*       hn32 = (u32*)&g_hx[(t + 1) & 1][0][0];

        const u64* hrow = hc + (size_t)skc * 64 + hb0;
        // stage chunks 0,1 directly; preload G-regs for chunks 2..5
        {
            const u64 g0 = aload(hrow);
            const u64 g1 = aload(hrow + 2048);
            ((u64*)sHraw)[swoff]        = g0;
            ((u64*)sHraw)[1088 + swoff] = g1;
        }
        u64 A = aload(hrow + 2 * 2048);
        u64 B = aload(hrow + 3 * 2048);
        u64 C = aload(hrow + 4 * 2048);
        u64 D = aload(hrow + 5 * 2048);

        // x for my epilogue cell (kh0 -> b, kh2 -> b+1), L1-warm
        float xv = 0.f;
        if ((kh & 1) == 0)
            xv = x[(size_t)(bloc + (kh >> 1)) * TLEN + t];

        barrier_lds();                  // chunks 0,1 staged; A..D stay in flight

        // prefetch chunk-0 operands (valid since the barrier above)
        const float* h0p_ = &sHraw[kc_ * 68 + bo8 * 8];
        float4 hAc = ld4(h0p_), hBc = ld4(h0p_ + 4);
        float4 hAn = make_float4(0.f, 0.f, 0.f, 0.f);
        float4 hBn = make_float4(0.f, 0.f, 0.f, 0.f);
        int bnF = 2176;                 // float base: prefetch buf (chunk p+1)
        int bwU = 2176;                 // u64 base: write buf (chunk p+2)

        float4 acc[2][8];   // [j_local][b]; components = 4 gates. STATIC indices only.
        #pragma unroll
        for (int jl = 0; jl < 2; ++jl)
            #pragma unroll
            for (int cb = 0; cb < 8; ++cb)
                acc[jl][cb] = make_float4(0.f, 0.f, 0.f, 0.f);

        #pragma unroll 1
        for (int i4 = 0; i4 < 32; i4 += 4) {
            PHASE(i4 + 0, A);
            PHASE(i4 + 1, B);
            PHASE(i4 + 2, C);
            PHASE(i4 + 3, D);
        }
        // last phase's barrier: all sH reads done -> sS alias safe

        // ---- intra-wave recursive-halving reduction over ks (56 shfl) ----
        float4 r1[8];
        #pragma unroll
        for (int i = 0; i < 8; ++i) {
            const float4 fs = (ks & 4) ? acc[0][i] : acc[1][i];
            float4 fr;
            fr.x = __shfl_xor(fs.x, 4); fr.y = __shfl_xor(fs.y, 4);
            fr.z = __shfl_xor(fs.z, 4); fr.w = __shfl_xor(fs.w, 4);
            const float4 fk = (ks & 4) ? acc[1][i] : acc[0][i];
            r1[i] = make_float4(fk.x + fr.x, fk.y + fr.y, fk.z + fr.z, fk.w + fr.w);
        }
        float4 r2[4];
        #pragma unroll
        for (int i = 0; i < 4; ++i) {
            const float4 fs = (ks & 2) ? r1[i] : r1[i + 4];
            float4 fr;
            fr.x = __shfl_xor(fs.x, 2); fr.y = __shfl_xor(fs.y, 2);
            fr.z = __shfl_xor(fs.z, 2); fr.w = __shfl_xor(fs.w, 2);
            const float4 fk = (ks & 2) ? r1[i + 4] : r1[i];
            r2[i] = make_float4(fk.x + fr.x, fk.y + fr.y, fk.z + fr.z, fk.w + fr.w);
        }
        float4 q0, q1;
        {
            const float4 fs0 = (ks & 1) ? r2[0] : r2[2];
            const float4 fs1 = (ks & 1) ? r2[1] : r2[3];
            float4 fr0, fr1;
            fr0.x = __shfl_xor(fs0.x, 1); fr0.y = __shfl_xor(fs0.y, 1);
            fr0.z = __shfl_xor(fs0.z, 1); fr0.w = __shfl_xor(fs0.w, 1);
            fr1.x = __shfl_xor(fs1.x, 1); fr1.y = __shfl_xor(fs1.y, 1);
            fr1.z = __shfl_xor(fs1.z, 1); fr1.w = __shfl_xor(fs1.w, 1);
            const float4 fk0 = (ks & 1) ? r2[2] : r2[0];
            const float4 fk1 = (ks & 1) ? r2[3] : r2[1];
            q0 = make_float4(fk0.x + fr0.x, fk0.y + fr0.y, fk0.z + fr0.z, fk0.w + fr0.w);
            q1 = make_float4(fk1.x + fr1.x, fk1.y + fr1.y, fk1.z + fr1.z, fk1.w + fr1.w);
        }
        // q0,q1 = partial (this kh) preacts for cells (jc, bloc) and (jc, bloc+1)

        // ---- cross-kh reduction via LDS aliased onto dead sH ----
        float4* sS = (float4*)sHraw;    // 1024 f4 = 16 KB <= 26 KB
        if (kh & 1) {                   // kh1 -> slot(jq,0), kh3 -> slot(jq,1)
            const int sl = ((jq * 2 + (kh >> 1)) * 64 + lane) * 2;
            sS[sl]     = q0;
            sS[sl + 1] = q1;
        }
        barrier_lds();
        if ((kh & 1) == 0) {            // kh0 adds kh1; kh2 adds kh3
            const int sl = ((jq * 2 + (kh >> 1)) * 64 + lane) * 2;
            ADD4(q0, sS[sl]);
            ADD4(q1, sS[sl + 1]);
        }
        // stage 2: kh0 surrenders q1, kh2 surrenders q0 (each keeps its cell)
        if (kh == 0) sS[((jq * 2 + 0) * 64 + lane) * 2 + 1] = q1;
        if (kh == 2) sS[((jq * 2 + 1) * 64 + lane) * 2 + 0] = q0;
        barrier_lds();

        if ((kh & 1) == 0) {
            float4 qq;
            if (kh == 0) {
                ADD4(q0, sS[((jq * 2 + 1) * 64 + lane) * 2 + 0]);
                qq = q0;
            } else {
                ADD4(q1, sS[((jq * 2 + 0) * 64 + lane) * 2 + 1]);
                qq = q1;
            }
            FMA4(qq, xv, wx4);
            qq.x += b4.x; qq.y += b4.y; qq.z += b4.z; qq.w += b4.w;
            const float g_ = tanhf(qq.x);
            const float i_ = 1.f / (1.f + expf(-qq.y));
            const float f_ = 1.f / (1.f + expf(-qq.z));
            const float o_ = 1.f / (1.f + expf(-qq.w));
            cst = g_ * i_ + cst * f_;
            const float hv = tanhf(cst) * o_;
            u32 bits; __builtin_memcpy(&bits, &hv, 4);
            astore32(hn32 + (size_t)jc * 128 + bloc + (kh >> 1), bits);
        }

        gbar2(flags, bgB, rgB, (u32)(t + 2));
    } // t
#undef PHASE

    // ---- final projection: out = h_final @ W_ph + bias_p (final h in buf 0).
    // Group-confinement: block projects b = bgB*64 + rgB (own b-half).
    if (rgB < 64) {
        const int b = bgB * 64 + rgB;
        float part[CDIM];
        #pragma unroll
        for (int c2 = 0; c2 < CDIM; ++c2) part[c2] = 0.f;
        for (int k = tid; k < HDIM; k += NT) {
            const u64 hvu = aload(&g_hx[0][k][b >> 1]);
            float2 hv2; __builtin_memcpy(&hv2, &hvu, 8);
            const float hvv = (b & 1) ? hv2.y : hv2.x;
            #pragma unroll
            for (int c2 = 0; c2 < CDIM; ++c2)
                part[c2] = fmaf(hvv, Wph[(size_t)k * CDIM + c2], part[c2]);
        }
        float* red = (float*)&sW[0][0][0];   // reuse dead W LDS (48 KB needed)
        #pragma unroll
        for (int c2 = 0; c2 < CDIM; ++c2) red[tid * 12 + c2] = part[c2];
        __syncthreads();
        for (int s = NT / 2; s > 0; s >>= 1) {
            if (tid < s) {
                #pragma unroll
                for (int c2 = 0; c2 < CDIM; ++c2)
                    red[tid * 12 + c2] += red[(tid + s) * 12 + c2];
            }
            __syncthreads();
        }
        if (tid < CDIM) out[(size_t)b * CDIM + tid] = red[tid] + bp[tid];
    }
}

extern "C" void kernel_launch(void* const* d_in, const int* in_sizes, int n_in,
                              void* d_out, int out_size, void* d_ws, size_t ws_size,
                              hipStream_t stream) {
    const float* x   = (const float*)d_in[0];
    const float* Wgx = (const float*)d_in[1];
    const float* Wgh = (const float*)d_in[2];
    const float* bg  = (const float*)d_in[3];
    const float* Wix = (const float*)d_in[4];
    const float* Wih = (const float*)d_in[5];
    const float* bi  = (const float*)d_in[6];
    const float* Wfx = (const float*)d_in[7];
    const float* Wfh = (const float*)d_in[8];
    const float* bf  = (const float*)d_in[9];
    const float* Wox = (const float*)d_in[10];
    const float* Woh = (const float*)d_in[11];
    const float* bo  = (const float*)d_in[12];
    const float* Wph = (const float*)d_in[13];
    const float* bp  = (const float*)d_in[14];
    u32* flags = (u32*)d_ws;               // u32[2][128] monotonic arrival flags
    float* out = (float*)d_out;

    (void)hipMemsetAsync(d_ws, 0, 2 * 128 * sizeof(u32), stream);   // capturable node

    void* args[] = {&x, &Wgx, &Wgh, &bg, &Wix, &Wih, &bi, &Wfx, &Wfh, &bf,
                    &Wox, &Woh, &bo, &Wph, &bp, &flags, &out};
    hipError_t rc = hipLaunchCooperativeKernel((void*)lstm_fused, dim3(NWG), dim3(NT),
                                               args, 0, stream);
    if (rc != hipSuccess) {
        // Custom barrier needs no cooperative-runtime support; 256 blocks at
        // 1 block/CU are fully co-resident under a regular launch too.
        lstm_fused<<<dim3(NWG), dim3(NT), 0, stream>>>(
            x, Wgx, Wgh, bg, Wix, Wih, bi, Wfx, Wfh, bf,
            Wox, Woh, bo, Wph, bp, flags, out);
    }
}

// Round 7
// 6190.142 us; speedup vs baseline: 23.0175x; 2.2452x over previous
//
#include <hip/hip_runtime.h>
#include <cmath>

#define BATCH 128
#define TLEN  256
#define HDIM  1024
#define CDIM  10
#define NT    1024
#define NWG   256

typedef unsigned long long u64;
typedef unsigned int u32;

// h state, double buffered, k-major, u64 = 2 packed floats: g_hx[buf][j][b/2].
// ALL h accesses are relaxed agent-scope atomics (sc1) -> no cache fences;
// x/W/bias stay warm in L1/L2 across all 256 steps.
__device__ u64 g_hx[2][HDIM][BATCH / 2];

__device__ __forceinline__ float4 ld4(const float* p) { return *(const float4*)p; }

__device__ __forceinline__ u64 aload(const u64* p) {
    return __hip_atomic_load(p, __ATOMIC_RELAXED, __HIP_MEMORY_SCOPE_AGENT);
}
__device__ __forceinline__ void astore(u64* p, u64 v) {
    __hip_atomic_store(p, v, __ATOMIC_RELAXED, __HIP_MEMORY_SCOPE_AGENT);
}
__device__ __forceinline__ void astore32(u32* p, u32 v) {
    __hip_atomic_store(p, v, __ATOMIC_RELAXED, __HIP_MEMORY_SCOPE_AGENT);
}

// R13: LDS-only barrier (intra-block barriers only protect LDS handoffs).
__device__ __forceinline__ void barrier_lds() {
    asm volatile("s_waitcnt lgkmcnt(0)\n\ts_barrier" ::: "memory");
}

// Group barrier (R11/R12-proven): parallel arrivals on 128 distinct flags,
// per-wave self-release poll, monotonic targets, bounded spin.
// Keeps its explicit vmcnt(0): it is the h-publish release fence.
__device__ __forceinline__ void gbar2(u32* flags, int grp, int idx, u32 target) {
    asm volatile("s_waitcnt vmcnt(0)" ::: "memory");
    __syncthreads();
    if (threadIdx.x == 0)
        astore32(flags + grp * 128 + idx, target);
    const u64* base = (const u64*)(flags + grp * 128) + (threadIdx.x & 63);
    int guard = 0;
    for (;;) {
        const u64 v = aload(base);
        const bool ok = ((u32)v >= target) && ((u32)(v >> 32) >= target);
        if (__all(ok) || ++guard > (1 << 20)) break;
        __builtin_amdgcn_s_sleep(1);
    }
}

#define FMA4(d, s, v) do { (d).x = fmaf((s), (v).x, (d).x); (d).y = fmaf((s), (v).y, (d).y); \
                           (d).z = fmaf((s), (v).z, (d).z); (d).w = fmaf((s), (v).w, (d).w); } while (0)
#define ADD4(d, s)     do { (d).x += (s).x; (d).y += (s).y; (d).z += (s).z; (d).w += (s).w; } while (0)

// R17: distance-1 register prefetch inside the PROVEN 2-buffer structure.
// Phase p: [1] prefetch chunk p+1 operands from buf (p+1)%2 (written phase p-1,
// barrier between); [2] ds_write chunk p+2 into buf p%2 (last read phase p-1's
// prefetch, barrier between; next read phase p+1's prefetch, barrier between);
// [3] reissue global load chunk p+4 (baseline cadence, <=2 outstanding);
// [4] FMA chunk p from regs prefetched in phase p-1. R16 lesson: VGPR budget
// at launch_bounds(1024,1) is 128; this adds ONLY hAn/hBn (+8) vs baseline.
// Spill diagnostic: WRITE_SIZE blowup (scratch lives in HBM).
__global__ void __launch_bounds__(NT, 1)
lstm_fused(const float* __restrict__ x,
           const float* __restrict__ Wgx, const float* __restrict__ Wgh, const float* __restrict__ bg,
           const float* __restrict__ Wix, const float* __restrict__ Wih, const float* __restrict__ bi,
           const float* __restrict__ Wfx, const float* __restrict__ Wfh, const float* __restrict__ bf,
           const float* __restrict__ Wox, const float* __restrict__ Woh, const float* __restrict__ bo,
           const float* __restrict__ Wph, const float* __restrict__ bp,
           u32* __restrict__ flags, float* __restrict__ out)
{
    __shared__ float sW[8][HDIM][4];            // [j_local][k][gate], 128 KB
    __shared__ __align__(16) float sHraw[2 * 32 * 68];   // h dbuf, 17 KB; aliased by sS after last phase
#define SH(B, K) (&sHraw[(B) * 2176 + (K) * 68])

    const int tid  = threadIdx.x;
    const int wave = tid >> 6;          // 0..15
    const int jq   = wave >> 2;         // j-pair index (0..3)
    const int kh   = wave & 3;          // k-quarter within chunk
    const int lane = tid & 63;
    const int ks   = lane & 7;
    const int bo8  = lane >> 3;
    const int rgB  = blockIdx.x >> 1;   // j in [8*rgB, 8*rgB+8)  == index in group
    const int bgB  = blockIdx.x & 1;    // b in [64*bgB, 64*bgB+64) == group id

    // ---- stage W once, gate-interleaved (1024 threads: 4 rows per pass) ----
    {
        auto stageW = [&](const float* Wsrc, int g) {
            #pragma unroll
            for (int it = 0; it < 2; ++it) {
                const int row = it * 4 + (tid >> 8);     // 0..7
                const int c4  = tid & 255;               // float4 column
                const float4 v = ld4(Wsrc + (size_t)(rgB * 8 + row) * HDIM + c4 * 4);
                sW[row][c4 * 4 + 0][g] = v.x;
                sW[row][c4 * 4 + 1][g] = v.y;
                sW[row][c4 * 4 + 2][g] = v.z;
                sW[row][c4 * 4 + 3][g] = v.w;
            }
        };
        stageW(Wgh, 0); stageW(Wih, 1); stageW(Wfh, 2); stageW(Woh, 3);
    }

    // epilogue cells: j = rgB*8 + jq*2 + (ks>>2); b = bgB*64 + bo8*8 + (ks&3)*2 + cell.
    const int jc = rgB * 8 + jq * 2 + (ks >> 2);
    const float4 wx4 = make_float4(Wgx[jc], Wix[jc], Wfx[jc], Wox[jc]);
    const float4 b4  = make_float4(bg[jc], bi[jc], bf[jc], bo[jc]);
    const int bloc = bgB * 64 + bo8 * 8 + (ks & 3) * 2;   // cell-0 batch index
    float cst = 0.f;                                       // my cell's c-state

    // zero h0 -- OWN b-half only: 8 j-rows x 32 u64
    if (tid < 256)
        astore(&g_hx[0][rgB * 8 + (tid >> 5)][bgB * 32 + (tid & 31)], 0ull);

    gbar2(flags, bgB, rgB, 1u);

    const int skc = tid >> 5;                   // staging: k within chunk (0..31)
    const int sbu = tid & 31;                   // staging: u64 col within 32
    const int hb0 = bgB * 32 + sbu;             // staging: u64 offset in g_hx row
    const int swA = 0;                          // buf0 base (u64 units)
    const int swB = 1088;                       // buf1 base
    const int swoff = skc * 34 + sbu;
    const int kc_ = kh * 8 + ks;                // this lane's k within any chunk

    // PH(P, G, SB, NB): [1] prefetch chunk P+1 from float-base NB; [2] ds_write
    // chunk P+2 (= G) at u64-base SB (buf P%2); [3] G = load chunk P+4;
    // [4] FMA chunk P from hAc/hBc (identical sequence to proven COMP).
#define PH(P, G, SB, NB)                                                        \
    {                                                                           \
        if ((P) + 1 < 32) {                                                     \
            const float* pp_ = &sHraw[(NB) + kc_ * 68 + bo8 * 8];               \
            hAn = ld4(pp_); hBn = ld4(pp_ + 4);                                 \
        }                                                                       \
        if ((P) + 2 < 32) ((u64*)sHraw)[(SB) + swoff] = G;                      \
        if ((P) + 4 < 32) G = aload(hrow + (size_t)((P) + 4) * 2048);           \
        {                                                                       \
            const float4 w0 = ld4(&sW[jq * 2 + 0][(P) * 32 + kc_][0]);          \
            const float4 w1 = ld4(&sW[jq * 2 + 1][(P) * 32 + kc_][0]);          \
            FMA4(acc[0][0], hAc.x, w0); FMA4(acc[0][1], hAc.y, w0);             \
            FMA4(acc[0][2], hAc.z, w0); FMA4(acc[0][3], hAc.w, w0);             \
            FMA4(acc[0][4], hBc.x, w0); FMA4(acc[0][5], hBc.y, w0);             \
            FMA4(acc[0][6], hBc.z, w0); FMA4(acc[0][7], hBc.w, w0);             \
            FMA4(acc[1][0], hAc.x, w1); FMA4(acc[1][1], hAc.y, w1);             \
            FMA4(acc[1][2], hAc.z, w1); FMA4(acc[1][3], hAc.w, w1);             \
            FMA4(acc[1][4], hBc.x, w1); FMA4(acc[1][5], hBc.y, w1);             \
            FMA4(acc[1][6], hBc.z, w1); FMA4(acc[1][7], hBc.w, w1);             \
        }                                                                       \
        barrier_lds();                                                          \
        hAc = hAn; hBc = hBn;                                                   \
    }

    for (int t = 0; t < TLEN; ++t) {
        const u64* hc = &g_hx[t & 1][0][0];
        u32*       hn32 = (u32*)&g_hx[(t + 1) & 1][0][0];

        const u64* hrow = hc + (size_t)skc * 64 + hb0;
        // prologue: stage chunks 0,1 directly; preload A,B with chunks 2,3
        {
            const u64 g0 = aload(hrow);
            const u64 g1 = aload(hrow + 2048);
            ((u64*)sHraw)[swA + swoff] = g0;
            ((u64*)sHraw)[swB + swoff] = g1;
        }
        u64 A = aload(hrow + 2 * 2048);
        u64 B = aload(hrow + 3 * 2048);

        // x for my epilogue cell (kh0 -> b, kh2 -> b+1), L1-warm
        float xv = 0.f;
        if ((kh & 1) == 0)
            xv = x[(size_t)(bloc + (kh >> 1)) * TLEN + t];

        barrier_lds();                  // chunks 0,1 staged; A,B stay in flight

        // reg-prefetch chunk 0 (epoch protected by the next barrier: phase 0's
        // ds_write into buf0 must not overlap these buf0 reads)
        float4 hAc, hBc;
        {
            const float* h0p_ = &sHraw[kc_ * 68 + bo8 * 8];
            hAc = ld4(h0p_); hBc = ld4(h0p_ + 4);
        }
        barrier_lds();

        float4 hAn = make_float4(0.f, 0.f, 0.f, 0.f);
        float4 hBn = make_float4(0.f, 0.f, 0.f, 0.f);

        float4 acc[2][8];   // [j_local][b]; components = 4 gates. STATIC indices only.
        #pragma unroll
        for (int jl = 0; jl < 2; ++jl)
            #pragma unroll
            for (int cb = 0; cb < 8; ++cb)
                acc[jl][cb] = make_float4(0.f, 0.f, 0.f, 0.f);

        #pragma unroll 1
        for (int cc = 0; cc < 16; ++cc) {
            const int e0 = cc * 2;
            PH(e0,     A, swA, 2176);   // even phase: write buf0, prefetch from buf1
            PH(e0 + 1, B, swB, 0);      // odd  phase: write buf1, prefetch from buf0
        }
        // last phase's barrier: all sH reads done -> sS alias safe

        // ---- intra-wave recursive-halving reduction over ks (56 shfl) ----
        float4 r1[8];
        #pragma unroll
        for (int i = 0; i < 8; ++i) {
            const float4 fs = (ks & 4) ? acc[0][i] : acc[1][i];
            float4 fr;
            fr.x = __shfl_xor(fs.x, 4); fr.y = __shfl_xor(fs.y, 4);
            fr.z = __shfl_xor(fs.z, 4); fr.w = __shfl_xor(fs.w, 4);
            const float4 fk = (ks & 4) ? acc[1][i] : acc[0][i];
            r1[i] = make_float4(fk.x + fr.x, fk.y + fr.y, fk.z + fr.z, fk.w + fr.w);
        }
        float4 r2[4];
        #pragma unroll
        for (int i = 0; i < 4; ++i) {
            const float4 fs = (ks & 2) ? r1[i] : r1[i + 4];
            float4 fr;
            fr.x = __shfl_xor(fs.x, 2); fr.y = __shfl_xor(fs.y, 2);
            fr.z = __shfl_xor(fs.z, 2); fr.w = __shfl_xor(fs.w, 2);
            const float4 fk = (ks & 2) ? r1[i + 4] : r1[i];
            r2[i] = make_float4(fk.x + fr.x, fk.y + fr.y, fk.z + fr.z, fk.w + fr.w);
        }
        float4 q0, q1;
        {
            const float4 fs0 = (ks & 1) ? r2[0] : r2[2];
            const float4 fs1 = (ks & 1) ? r2[1] : r2[3];
            float4 fr0, fr1;
            fr0.x = __shfl_xor(fs0.x, 1); fr0.y = __shfl_xor(fs0.y, 1);
            fr0.z = __shfl_xor(fs0.z, 1); fr0.w = __shfl_xor(fs0.w, 1);
            fr1.x = __shfl_xor(fs1.x, 1); fr1.y = __shfl_xor(fs1.y, 1);
            fr1.z = __shfl_xor(fs1.z, 1); fr1.w = __shfl_xor(fs1.w, 1);
            const float4 fk0 = (ks & 1) ? r2[2] : r2[0];
            const float4 fk1 = (ks & 1) ? r2[3] : r2[1];
            q0 = make_float4(fk0.x + fr0.x, fk0.y + fr0.y, fk0.z + fr0.z, fk0.w + fr0.w);
            q1 = make_float4(fk1.x + fr1.x, fk1.y + fr1.y, fk1.z + fr1.z, fk1.w + fr1.w);
        }
        // q0,q1 = partial (this kh) preacts for cells (jc, bloc) and (jc, bloc+1)

        // ---- cross-kh reduction via LDS aliased onto dead sH ----
        float4* sS = (float4*)sHraw;    // 1024 f4 = 16 KB <= 17.4 KB
        if (kh & 1) {                   // kh1 -> slot(jq,0), kh3 -> slot(jq,1)
            const int sl = ((jq * 2 + (kh >> 1)) * 64 + lane) * 2;
            sS[sl]     = q0;
            sS[sl + 1] = q1;
        }
        barrier_lds();
        if ((kh & 1) == 0) {            // kh0 adds kh1; kh2 adds kh3
            const int sl = ((jq * 2 + (kh >> 1)) * 64 + lane) * 2;
            ADD4(q0, sS[sl]);
            ADD4(q1, sS[sl + 1]);
        }
        // stage 2: kh0 surrenders q1, kh2 surrenders q0 (each keeps its cell)
        if (kh == 0) sS[((jq * 2 + 0) * 64 + lane) * 2 + 1] = q1;
        if (kh == 2) sS[((jq * 2 + 1) * 64 + lane) * 2 + 0] = q0;
        barrier_lds();

        if ((kh & 1) == 0) {
            float4 qq;
            if (kh == 0) {
                ADD4(q0, sS[((jq * 2 + 1) * 64 + lane) * 2 + 0]);
                qq = q0;
            } else {
                ADD4(q1, sS[((jq * 2 + 0) * 64 + lane) * 2 + 1]);
                qq = q1;
            }
            FMA4(qq, xv, wx4);
            qq.x += b4.x; qq.y += b4.y; qq.z += b4.z; qq.w += b4.w;
            const float g_ = tanhf(qq.x);
            const float i_ = 1.f / (1.f + expf(-qq.y));
            const float f_ = 1.f / (1.f + expf(-qq.z));
            const float o_ = 1.f / (1.f + expf(-qq.w));
            cst = g_ * i_ + cst * f_;
            const float hv = tanhf(cst) * o_;
            u32 bits; __builtin_memcpy(&bits, &hv, 4);
            astore32(hn32 + (size_t)jc * 128 + bloc + (kh >> 1), bits);
        }

        gbar2(flags, bgB, rgB, (u32)(t + 2));
    } // t
#undef PH

    // ---- final projection: out = h_final @ W_ph + bias_p (final h in buf 0).
    // Group-confinement: block projects b = bgB*64 + rgB (own b-half).
    if (rgB < 64) {
        const int b = bgB * 64 + rgB;
        float part[CDIM];
        #pragma unroll
        for (int c2 = 0; c2 < CDIM; ++c2) part[c2] = 0.f;
        for (int k = tid; k < HDIM; k += NT) {
            const u64 hvu = aload(&g_hx[0][k][b >> 1]);
            float2 hv2; __builtin_memcpy(&hv2, &hvu, 8);
            const float hvv = (b & 1) ? hv2.y : hv2.x;
            #pragma unroll
            for (int c2 = 0; c2 < CDIM; ++c2)
                part[c2] = fmaf(hvv, Wph[(size_t)k * CDIM + c2], part[c2]);
        }
        float* red = (float*)&sW[0][0][0];   // reuse dead W LDS (48 KB needed)
        #pragma unroll
        for (int c2 = 0; c2 < CDIM; ++c2) red[tid * 12 + c2] = part[c2];
        __syncthreads();
        for (int s = NT / 2; s > 0; s >>= 1) {
            if (tid < s) {
                #pragma unroll
                for (int c2 = 0; c2 < CDIM; ++c2)
                    red[tid * 12 + c2] += red[(tid + s) * 12 + c2];
            }
            __syncthreads();
        }
        if (tid < CDIM) out[(size_t)b * CDIM + tid] = red[tid] + bp[tid];
    }
}

extern "C" void kernel_launch(void* const* d_in, const int* in_sizes, int n_in,
                              void* d_out, int out_size, void* d_ws, size_t ws_size,
                              hipStream_t stream) {
    const float* x   = (const float*)d_in[0];
    const float* Wgx = (const float*)d_in[1];
    const float* Wgh = (const float*)d_in[2];
    const float* bg  = (const float*)d_in[3];
    const float* Wix = (const float*)d_in[4];
    const float* Wih = (const float*)d_in[5];
    const float* bi  = (const float*)d_in[6];
    const float* Wfx = (const float*)d_in[7];
    const float* Wfh = (const float*)d_in[8];
    const float* bf  = (const float*)d_in[9];
    const float* Wox = (const float*)d_in[10];
    const float* Woh = (const float*)d_in[11];
    const float* bo  = (const float*)d_in[12];
    const float* Wph = (const float*)d_in[13];
    const float* bp  = (const float*)d_in[14];
    u32* flags = (u32*)d_ws;               // u32[2][128] monotonic arrival flags
    float* out = (float*)d_out;

    (void)hipMemsetAsync(d_ws, 0, 2 * 128 * sizeof(u32), stream);   // capturable node

    void* args[] = {&x, &Wgx, &Wgh, &bg, &Wix, &Wih, &bi, &Wfx, &Wfh, &bf,
                    &Wox, &Woh, &bo, &Wph, &bp, &flags, &out};
    hipError_t rc = hipLaunchCooperativeKernel((void*)lstm_fused, dim3(NWG), dim3(NT),
                                               args, 0, stream);
    if (rc != hipSuccess) {
        // Custom barrier needs no cooperative-runtime support; 256 blocks at
        // 1 block/CU are fully co-resident under a regular launch too.
        lstm_fused<<<dim3(NWG), dim3(NT), 0, stream>>>(
            x, Wgx, Wgh, bg, Wix, Wih, bi, Wfx, Wfh, bf,
            Wox, Woh, bo, Wph, bp, flags, out);
    }
}